// Round 1
// baseline (25.156 us; speedup 1.0000x reference)
//
#include <hip/hip_runtime.h>

// Problem constants (from reference):
//   BATCH=8, SEQ_LEN=2048, D_MODEL=1024, PERIOD=24
// attn_mat == identity (only integer-distance 0 survives the dist>=1 cutoff),
// period_mat == ones on the +/-24 off-diagonals.
// => out[b,s,:] = qz[b,s-24,:] + qz[b,s+24,:]  (terms dropped when out of range)

constexpr int BATCH  = 8;
constexpr int SEQ    = 2048;
constexpr int DM     = 1024;
constexpr int PERIOD = 24;
constexpr int DV     = DM / 4;               // float4s per row = 256
constexpr int TOTALV = BATCH * SEQ * DV;     // 4,194,304 float4 elements
constexpr int ROW_SHIFT = 8;                 // log2(DV)

__global__ __launch_bounds__(256) void ptperiod_shift_add(
        const float4* __restrict__ qz, float4* __restrict__ out) {
    const int stride = gridDim.x * blockDim.x;
    for (int i = blockIdx.x * blockDim.x + threadIdx.x; i < TOTALV; i += stride) {
        const int row = i >> ROW_SHIFT;      // global row index b*SEQ + s
        const int s   = row & (SEQ - 1);     // SEQ is pow2
        float4 r = make_float4(0.f, 0.f, 0.f, 0.f);
        if (s >= PERIOD) {
            const float4 a = qz[i - PERIOD * DV];
            r.x += a.x; r.y += a.y; r.z += a.z; r.w += a.w;
        }
        if (s < SEQ - PERIOD) {
            const float4 b = qz[i + PERIOD * DV];
            r.x += b.x; r.y += b.y; r.z += b.z; r.w += b.w;
        }
        out[i] = r;
    }
}

extern "C" void kernel_launch(void* const* d_in, const int* in_sizes, int n_in,
                              void* d_out, int out_size, void* d_ws, size_t ws_size,
                              hipStream_t stream) {
    const float4* qz  = (const float4*)d_in[0];   // [8,2048,1024] f32
    float4*       out = (float4*)d_out;           // [8,2048,1024] f32

    const int threads = 256;
    const int blocks  = 2048;                      // grid-stride covers 4.19M float4s
    hipLaunchKernelGGL(ptperiod_shift_add, dim3(blocks), dim3(threads), 0, stream,
                       qz, out);
}

// Round 2
// 24.355 us; speedup vs baseline: 1.0329x; 1.0329x over previous
//
#include <hip/hip_runtime.h>

// Problem constants (from reference):
//   BATCH=8, SEQ_LEN=2048, D_MODEL=1024, PERIOD=24
// attn_mat == identity (integer distances: only dist==0 survives the dist>=1 cutoff),
// period_mat == ones on the +/-24 off-diagonals.
// => out[b,s,:] = qz[b,s-24,:] + qz[b,s+24,:]  (terms dropped when out of range)
//
// Pure memory-bound shift-add. Floor: 64 MiB read + 64 MiB write @ ~6.3 TB/s ≈ 21 µs.

constexpr int BATCH  = 8;
constexpr int SEQ    = 2048;
constexpr int DM     = 1024;
constexpr int PERIOD = 24;
constexpr int DV     = DM / 4;               // float4s per row = 256
constexpr int TOTALV = BATCH * SEQ * DV;     // 4,194,304 float4 elements
constexpr int BLOCKS  = 2048;
constexpr int THREADS = 256;
constexpr int SWEEP   = BLOCKS * THREADS;    // 524,288 -> exactly 8 sweeps
constexpr int NSWEEP  = TOTALV / SWEEP;      // 8 (exact)

typedef float f32x4 __attribute__((ext_vector_type(4)));

__global__ __launch_bounds__(256) void ptperiod_shift_add(
        const f32x4* __restrict__ qz, f32x4* __restrict__ out) {
    const int base = blockIdx.x * THREADS + threadIdx.x;
    // Compile-time trip count: fully unrolled so all loads issue up front
    // (batched vmcnt drain) instead of one load/store/waitcnt per iteration.
#pragma unroll
    for (int k = 0; k < NSWEEP; ++k) {
        const int i = base + k * SWEEP;
        const int s = (i >> 8) & (SEQ - 1);  // seq position (row = i>>8, SEQ pow2)
        f32x4 r = (f32x4){0.f, 0.f, 0.f, 0.f};
        if (s >= PERIOD)       r += qz[i - PERIOD * DV];
        if (s < SEQ - PERIOD)  r += qz[i + PERIOD * DV];
        // Output is never re-read: non-temporal store keeps L2/L3 for qz
        // (2x read reuse at 96 KB distance + cross-replay L3 residency).
        __builtin_nontemporal_store(r, &out[i]);
    }
}

extern "C" void kernel_launch(void* const* d_in, const int* in_sizes, int n_in,
                              void* d_out, int out_size, void* d_ws, size_t ws_size,
                              hipStream_t stream) {
    const f32x4* qz  = (const f32x4*)d_in[0];   // [8,2048,1024] f32
    f32x4*       out = (f32x4*)d_out;           // [8,2048,1024] f32

    hipLaunchKernelGGL(ptperiod_shift_add, dim3(BLOCKS), dim3(THREADS), 0, stream,
                       qz, out);
}

// Round 3
// 24.344 us; speedup vs baseline: 1.0333x; 1.0004x over previous
//
#include <hip/hip_runtime.h>

// out[b,s,:] = qz[b,s-24,:] + qz[b,s+24,:]   (terms dropped out of range)
// attn_mat == identity, period_mat == +/-24 shift. Pure memory-bound shift-add.
// Traffic floor: 64 MiB read + 64 MiB write; copy ceiling ~6.3 TB/s -> ~21 us.
//
// This round: occupancy fix. Unroll-4 (8 loads in flight = 32 data VGPRs) +
// __launch_bounds__(256,8) pins 32 waves/CU; 4096 blocks = 16 blocks/CU =
// exactly 2 clean resident rounds. TLP > deep ILP for streaming.

constexpr int SEQ    = 2048;
constexpr int PERIOD = 24;
constexpr int DV     = 1024 / 4;             // float4s per row = 256
constexpr int TOTALV = 8 * SEQ * DV;         // 4,194,304 float4 elements
constexpr int BLOCKS  = 4096;
constexpr int THREADS = 256;
constexpr int SWEEP   = BLOCKS * THREADS;    // 1,048,576 -> exactly 4 sweeps
constexpr int NSWEEP  = TOTALV / SWEEP;      // 4 (exact)

typedef float f32x4 __attribute__((ext_vector_type(4)));

__global__ __launch_bounds__(256, 8) void ptperiod_shift_add(
        const f32x4* __restrict__ qz, f32x4* __restrict__ out) {
    const int base = blockIdx.x * THREADS + threadIdx.x;
#pragma unroll
    for (int k = 0; k < NSWEEP; ++k) {
        const int i = base + k * SWEEP;
        const int s = (i >> 8) & (SEQ - 1);  // seq position (row = i>>8, SEQ pow2)
        f32x4 r = (f32x4){0.f, 0.f, 0.f, 0.f};
        if (s >= PERIOD)       r += qz[i - PERIOD * DV];
        if (s < SEQ - PERIOD)  r += qz[i + PERIOD * DV];
        // Output never re-read within a replay: NT store keeps L2/L3 for qz.
        __builtin_nontemporal_store(r, &out[i]);
    }
}

extern "C" void kernel_launch(void* const* d_in, const int* in_sizes, int n_in,
                              void* d_out, int out_size, void* d_ws, size_t ws_size,
                              hipStream_t stream) {
    const f32x4* qz  = (const f32x4*)d_in[0];   // [8,2048,1024] f32
    f32x4*       out = (f32x4*)d_out;           // [8,2048,1024] f32

    hipLaunchKernelGGL(ptperiod_shift_add, dim3(BLOCKS), dim3(THREADS), 0, stream,
                       qz, out);
}